// Round 10
// baseline (167.738 us; speedup 1.0000x reference)
//
#include <hip/hip_runtime.h>
#include <hip/hip_bf16.h>
#include <cstdint>

// MultiRelationalGraphDiffusion: out = LeakyReLU( sum_k conv_w[k] * (adj_norm^k @ (h@W^T)) + conv_b )
// B=8, N=2048, D=256, K=4.
//
// Round-10: LDS-FREE, BARRIER-FREE diffuse on FRAGMENT-MAJOR layouts.
// R6-R9 lesson (traffic math): staged bytes/step = adjq*(D/Ot) + c*(N/Mt); every LDS
// variant paid 128-192MB/step through L2/L3 (~12-16us). Fix: Ot=256 (A read ONCE,
// 32MB/step) and B direct global->register (c = 512KB/batch, L2-resident per XCD).
//  - afrag[b][nf][ks][lane*8B]: A-frag (16 rows x 32 k) = 512B contiguous.
//  - cfrag[b][ks][of][lane*8B]: B-frag (32 k x 16 cols) = 512B contiguous.
//  - k_diffuse: 256 blocks x 4 waves, wave = 16 rows x 256 cols. Per ksub: 1 A-frag +
//    16 B-frag loads + 16 MFMA; 4-deep register ping (static indices), compiler vmcnt.
//  - b = blockIdx&7 -> batch-per-XCD (round-robin): c + adjq slice L2-local.
// Scales: adjS=256*adj_norm, cS=16*c -> acc=4096*(adj@c); next cS=acc/256; last tap acc/4096.

#define BATCH 8
#define NN    2048
#define DD    256
#define REPS  1e-9f
#define SLOPE 0.2f

typedef __bf16 bf16x8_t __attribute__((ext_vector_type(8)));
typedef __bf16 bf16x4_t __attribute__((ext_vector_type(4)));
typedef float  f32x4_t  __attribute__((ext_vector_type(4)));

__device__ __forceinline__ unsigned int pk_fp8x4(float a, float b, float c, float d) {
    int lo = __builtin_amdgcn_cvt_pk_fp8_f32(a, b, 0, false);
    return (unsigned int)__builtin_amdgcn_cvt_pk_fp8_f32(c, d, lo, true);
}

__device__ __forceinline__ f32x4_t cvt_f32_fp8x4(unsigned int u) {
    f32x4_t r;
    r[0] = __builtin_amdgcn_cvt_f32_fp8(u, 0);
    r[1] = __builtin_amdgcn_cvt_f32_fp8(u, 1);
    r[2] = __builtin_amdgcn_cvt_f32_fp8(u, 2);
    r[3] = __builtin_amdgcn_cvt_f32_fp8(u, 3);
    return r;
}

__device__ __forceinline__ uint2 q8(f32x4_t a, f32x4_t b, float sc) {
    uint2 r;
    r.x = pk_fp8x4(a[0] * sc, a[1] * sc, a[2] * sc, a[3] * sc);
    r.y = pk_fp8x4(b[0] * sc, b[1] * sc, b[2] * sc, b[3] * sc);
    return r;
}

// c-frag address for the 4 packed values (n..n+3, col) starting at row0 (row0%4==0):
// frag (ks=row0>>5, of=col>>4), slot = (col&15) + 16*((row0>>3)&3), byte (row0&4)
__device__ __forceinline__ size_t cfrag_addr(int b, int row0, int col) {
    return ((size_t)(b * 64 + (row0 >> 5)) * 16 + (col >> 4)) * 512
         + ((col & 15) + 16 * ((row0 >> 3) & 3)) * 8 + (row0 & 4);
}

// ================= normadj: 16 rows/block, frag-major output via LDS transpose =================
__global__ __launch_bounds__(1024) void k_normadj(const float* __restrict__ adj,
                                                  unsigned char* __restrict__ afrag) {
    __shared__ __align__(16) unsigned char fr[64 * 520];   // 64 frags, padded to 520B
    const int w = threadIdx.x >> 6;           // row-in-block 0..15
    const int l = threadIdx.x & 63;
    const int n = blockIdx.x * 16 + w;        // global row (b*NN + row)
    const float* src = adj + (size_t)n * NN;
    // lane l holds k in [8l,8l+8) of each 512-chunk q -> k = 512q + 8l + e
    f32x4_t v[8];
#pragma unroll
    for (int q = 0; q < 4; ++q) {
        v[2 * q]     = *(const f32x4_t*)(src + q * 512 + l * 8);
        v[2 * q + 1] = *(const f32x4_t*)(src + q * 512 + l * 8 + 4);
    }
    float s = 0.f;
#pragma unroll
    for (int j = 0; j < 8; ++j) s += v[j][0] + v[j][1] + v[j][2] + v[j][3];
#pragma unroll
    for (int m = 1; m < 64; m <<= 1) s += __shfl_xor(s, m, 64);
    const float sc = 256.0f / (s + REPS);
    // chunk (q,l): frag ks = 16q + (l>>2), slot kq = l&3 -> k = 32ks+8kq+e = 512q+8l+e
#pragma unroll
    for (int q = 0; q < 4; ++q) {
        uint2 u = q8(v[2 * q], v[2 * q + 1], sc);
        *(uint2*)(fr + (16 * q + (l >> 2)) * 520 + w * 8 + (l & 3) * 128) = u;
    }
    __syncthreads();
    // store: wave w -> frags [4w,4w+4), 512B coalesced each
    unsigned char* dst = afrag + (size_t)blockIdx.x * 64 * 512;   // blockIdx = b*128+nf
#pragma unroll
    for (int f2 = 0; f2 < 4; ++f2) {
        const int f = w * 4 + f2;
        *(uint2*)(dst + (size_t)f * 512 + l * 8) = *(const uint2*)(fr + f * 520 + l * 8);
    }
}

// ================= htrans: bf16x3 MFMA; t_h fp16, c0 frag-major fp8(16t) =================
__device__ __forceinline__ void pair_remap(int& n0, int& o0, int& b) {
    const int p = blockIdx.x + 32 * (blockIdx.y + 2 * blockIdx.z);
    const int g = p >> 4, r = p & 15;
    o0 = (r >> 3) * 128;
    const int nb = g * 8 + (r & 7);
    n0 = (nb & 31) * 64;
    b  = nb >> 5;
}

__global__ __launch_bounds__(256) void k_htrans(const float* __restrict__ h,
                                                const float* __restrict__ W,
                                                _Float16* __restrict__ t_h,
                                                unsigned char* __restrict__ c0f) {
    __shared__ __align__(16) __bf16 Ah[64 * 64], Al[64 * 64];
    __shared__ __align__(16) __bf16 Bh[128 * 64], Bl[128 * 64];

    const int tid = threadIdx.x;
    int n0, o0, b;
    pair_remap(n0, o0, b);
    const int lane = tid & 63, wv = tid >> 6;
    const int wr = wv >> 1, wc = wv & 1;
    const int rl = lane & 15, kq = lane >> 4;
    const int ar = tid >> 4, ac = (tid & 15) * 4;

    f32x4_t acc[2][4];
#pragma unroll
    for (int i = 0; i < 2; ++i)
#pragma unroll
        for (int j = 0; j < 4; ++j) acc[i][j] = (f32x4_t){0.f, 0.f, 0.f, 0.f};

    for (int kt = 0; kt < 4; ++kt) {
        const int k0 = kt * 64;
#pragma unroll
        for (int q = 0; q < 4; ++q) {
            const int r = q * 16 + ar;
            f32x4_t v = *(const f32x4_t*)(h + ((size_t)b * NN + n0 + r) * DD + k0 + ac);
            bf16x4_t hi4, lo4;
#pragma unroll
            for (int e = 0; e < 4; ++e) {
                float x = v[e];
                __bf16 hh = (__bf16)x;
                hi4[e] = hh;
                lo4[e] = (__bf16)(x - (float)hh);
            }
            const int off = r * 128 + (((ac >> 3) ^ (r & 7)) << 4) + (ac & 7) * 2;
            *(bf16x4_t*)((char*)Ah + off) = hi4;
            *(bf16x4_t*)((char*)Al + off) = lo4;
        }
#pragma unroll
        for (int q = 0; q < 8; ++q) {
            const int r = q * 16 + ar;
            f32x4_t v = *(const f32x4_t*)(W + (size_t)(o0 + r) * DD + k0 + ac);
            bf16x4_t hi4, lo4;
#pragma unroll
            for (int e = 0; e < 4; ++e) {
                float x = v[e];
                __bf16 hh = (__bf16)x;
                hi4[e] = hh;
                lo4[e] = (__bf16)(x - (float)hh);
            }
            const int off = r * 128 + (((ac >> 3) ^ (r & 7)) << 4) + (ac & 7) * 2;
            *(bf16x4_t*)((char*)Bh + off) = hi4;
            *(bf16x4_t*)((char*)Bl + off) = lo4;
        }
        __syncthreads();
#pragma unroll
        for (int s = 0; s < 2; ++s) {
            bf16x8_t ah[2], al[2], bh[4], bl[4];
#pragma unroll
            for (int i = 0; i < 2; ++i) {
                const int row = wr * 32 + i * 16 + rl;
                const int byo = row * 128 + (((s * 4 + kq) ^ (row & 7)) << 4);
                ah[i] = *(const bf16x8_t*)((const char*)Ah + byo);
                al[i] = *(const bf16x8_t*)((const char*)Al + byo);
            }
#pragma unroll
            for (int j = 0; j < 4; ++j) {
                const int o = wc * 64 + j * 16 + rl;
                const int byo = o * 128 + (((s * 4 + kq) ^ (o & 7)) << 4);
                bh[j] = *(const bf16x8_t*)((const char*)Bh + byo);
                bl[j] = *(const bf16x8_t*)((const char*)Bl + byo);
            }
#pragma unroll
            for (int i = 0; i < 2; ++i)
#pragma unroll
                for (int j = 0; j < 4; ++j) {
                    acc[i][j] = __builtin_amdgcn_mfma_f32_16x16x32_bf16(ah[i], bh[j], acc[i][j], 0, 0, 0);
                    acc[i][j] = __builtin_amdgcn_mfma_f32_16x16x32_bf16(al[i], bh[j], acc[i][j], 0, 0, 0);
                    acc[i][j] = __builtin_amdgcn_mfma_f32_16x16x32_bf16(ah[i], bl[j], acc[i][j], 0, 0, 0);
                }
        }
        __syncthreads();
    }

#pragma unroll
    for (int i = 0; i < 2; ++i)
#pragma unroll
        for (int j = 0; j < 4; ++j) {
            const int row0 = n0 + wr * 32 + i * 16 + kq * 4;
            const int col  = o0 + wc * 64 + j * 16 + rl;
            _Float16* tp = t_h + ((size_t)b * NN + row0) * DD + col;
#pragma unroll
            for (int r2 = 0; r2 < 4; ++r2) tp[r2 * DD] = (_Float16)acc[i][j][r2];
            *(unsigned int*)(c0f + cfrag_addr(b, row0, col)) =
                pk_fp8x4(16.f * acc[i][j][0], 16.f * acc[i][j][1],
                         16.f * acc[i][j][2], 16.f * acc[i][j][3]);
        }
}

// ================= diffuse: LDS-free, barrier-free, frag-major streaming =================
template <bool LAST>
__global__ __launch_bounds__(256) void k_diffuse(const unsigned char* __restrict__ afrag,
                                                 const unsigned char* __restrict__ cin,
                                                 unsigned char* __restrict__ cout,
                                                 const unsigned char* __restrict__ c1f,
                                                 const unsigned char* __restrict__ c2f,
                                                 const _Float16* __restrict__ t_h,
                                                 float* __restrict__ out,
                                                 const float* __restrict__ convw,
                                                 const float* __restrict__ convb) {
    const int p = blockIdx.x;
    const int b = p & 7;                               // batch = XCD (round-robin)
    const int nf = (p >> 3) * 4 + (threadIdx.x >> 6);  // this wave's 16-row frag
    const int l = threadIdx.x & 63;
    const int rl = l & 15, kq = l >> 4;

    const unsigned char* Ap = afrag + ((size_t)(b * 128 + nf) * 64) * 512 + l * 8;
    const unsigned char* Cp = cin + ((size_t)b * 1024) * 512 + l * 8;   // 64 ks x 16 of

    f32x4_t acc[16];
#pragma unroll
    for (int of = 0; of < 16; ++of) acc[of] = (f32x4_t){0.f, 0.f, 0.f, 0.f};

    long ar0, ar1, ar2, ar3;
    long br0[16], br1[16], br2[16], br3[16];

#define LOADG(D, T)                                                                   \
    ar##D = *(const long*)(Ap + (size_t)(T) * 512);                                   \
    _Pragma("unroll") for (int of = 0; of < 16; ++of)                                 \
        br##D[of] = *(const long*)(Cp + ((size_t)(T) * 16 + of) * 512);

#define COMP(D)                                                                       \
    _Pragma("unroll") for (int of = 0; of < 16; ++of)                                 \
        acc[of] = __builtin_amdgcn_mfma_f32_16x16x32_fp8_fp8(ar##D, br##D[of], acc[of], 0, 0, 0);

    LOADG(0, 0) LOADG(1, 1) LOADG(2, 2) LOADG(3, 3)

    for (int t = 0; t < 64; t += 4) {
        COMP(0) LOADG(0, (t + 4) & 63)
        COMP(1) LOADG(1, (t + 5) & 63)
        COMP(2) LOADG(2, (t + 6) & 63)
        COMP(3) LOADG(3, (t + 7) & 63)
    }
#undef LOADG
#undef COMP

    // ---- epilogue: D frag col=lane&15 (of*16+rl), row=nf*16 + kq*4 + reg ----
    const int row0 = nf * 16 + kq * 4;
#pragma unroll
    for (int of = 0; of < 16; ++of) {
        const int col = of * 16 + rl;
        if (LAST) {
            const float cw0 = convw[0], cw1 = convw[1], cw2 = convw[2], cw3 = convw[3];
            const float cb  = convb[0];
            const float ru = 1.0f / 16.0f, rf = 1.0f / 4096.0f;
            float* op = out + ((size_t)b * NN + row0) * DD + col;
            const _Float16* tp = t_h + ((size_t)b * NN + row0) * DD + col;
            const size_t sa = cfrag_addr(b, row0, col);
            f32x4_t u1 = cvt_f32_fp8x4(*(const unsigned int*)(c1f + sa));
            f32x4_t u2 = cvt_f32_fp8x4(*(const unsigned int*)(c2f + sa));
#pragma unroll
            for (int r2 = 0; r2 < 4; ++r2) {
                float v = cw0 * (float)tp[r2 * DD] + cw1 * ru * u1[r2] + cw2 * ru * u2[r2]
                        + cw3 * rf * acc[of][r2] + cb;
                op[r2 * DD] = v >= 0.0f ? v : SLOPE * v;
            }
        } else {
            const float rs = 1.0f / 256.0f;   // acc -> 16*c_next
            *(unsigned int*)(cout + cfrag_addr(b, row0, col)) =
                pk_fp8x4(rs * acc[of][0], rs * acc[of][1], rs * acc[of][2], rs * acc[of][3]);
        }
    }
}

extern "C" void kernel_launch(void* const* d_in, const int* in_sizes, int n_in,
                              void* d_out, int out_size, void* d_ws, size_t ws_size,
                              hipStream_t stream) {
    const float* h   = (const float*)d_in[0];
    const float* adj = (const float*)d_in[1];
    const float* W   = (const float*)d_in[2];
    const float* cw  = (const float*)d_in[3];
    const float* cb  = (const float*)d_in[4];
    float* out = (float*)d_out;

    char* ws = (char*)d_ws;
    unsigned char* afrag = (unsigned char*)ws;                        // 32 MB
    unsigned char* c0f   = (unsigned char*)(ws + 33554432);           // 4 MB
    unsigned char* c1f   = (unsigned char*)(ws + 37748736);           // 4 MB
    unsigned char* c2f   = (unsigned char*)(ws + 41943040);           // 4 MB
    _Float16*      t_h   = (_Float16*)(ws + 46137344);                // 8.4 MB (~52.5 MB)

    k_normadj<<<BATCH * NN / 16, 1024, 0, stream>>>(adj, afrag);
    k_htrans<<<dim3(32, 2, BATCH), 256, 0, stream>>>(h, W, t_h, c0f);
    k_diffuse<false><<<256, 256, 0, stream>>>(afrag, c0f, c1f, nullptr, nullptr, nullptr, out, cw, cb);
    k_diffuse<false><<<256, 256, 0, stream>>>(afrag, c1f, c2f, nullptr, nullptr, nullptr, out, cw, cb);
    k_diffuse<true ><<<256, 256, 0, stream>>>(afrag, c2f, nullptr, c1f, c2f, t_h, out, cw, cb);
}

// Round 11
// 103.755 us; speedup vs baseline: 1.6167x; 1.6167x over previous
//
#include <hip/hip_runtime.h>
#include <hip/hip_bf16.h>
#include <cstdint>

// MultiRelationalGraphDiffusion: out = LeakyReLU( sum_k conv_w[k] * (adj_norm^k @ (h@W^T)) + conv_b )
// B=8, N=2048, D=256, K=4.
//
// Round-11: frag-major LDS diffuse. R10 lesson: frag-major GLOBAL layouts verified, but
// B-from-global-per-wave = 512 MB/step L2 + register blowup. R6-R10 bank-math lesson:
// row-major swizzled LDS gives 4-8-way conflicts on b64 frag reads (bank = f(chunk) only,
// row-independent). Fix: stage 512B-contiguous FRAGMENTS into LDS (coalesced gl2lds from
// contiguous global slab, linear dest); frag read = frag*512 + lane*8 -> 32 banks in 4
// clean phases, ZERO conflicts.
// Diffuse: 64n x 256o (R6's best geometry), BK=128, 512 thr, NBUF=3 (120 KB), ahead-2
// counted vmcnt(5), one s_barrier/iter. Ledger: stage(t+2 -> buf (t+2)%3) AFTER
// barrier(t) => all waves finished compute(t-1) (last reader of that buf); vmcnt(5)
// waits tile t, leaves 10 in flight (~2 K-steps cover >= 900cyc worst latency).
// Scales: adjS=256*adj_norm, cS=16*c -> acc=4096*(adj@c); next cS=acc/256; last tap acc/4096.

#define BATCH 8
#define NN    2048
#define DD    256
#define REPS  1e-9f
#define SLOPE 0.2f

typedef __bf16 bf16x8_t __attribute__((ext_vector_type(8)));
typedef __bf16 bf16x4_t __attribute__((ext_vector_type(4)));
typedef float  f32x4_t  __attribute__((ext_vector_type(4)));

__device__ __forceinline__ void gl2lds16(const void* g, void* l) {
    __builtin_amdgcn_global_load_lds(
        (const __attribute__((address_space(1))) unsigned int*)(uintptr_t)g,
        (__attribute__((address_space(3))) unsigned int*)(unsigned int)(uintptr_t)l,
        16, 0, 0);
}

__device__ __forceinline__ unsigned int pk_fp8x4(float a, float b, float c, float d) {
    int lo = __builtin_amdgcn_cvt_pk_fp8_f32(a, b, 0, false);
    return (unsigned int)__builtin_amdgcn_cvt_pk_fp8_f32(c, d, lo, true);
}

__device__ __forceinline__ f32x4_t cvt_f32_fp8x4(unsigned int u) {
    f32x4_t r;
    r[0] = __builtin_amdgcn_cvt_f32_fp8(u, 0);
    r[1] = __builtin_amdgcn_cvt_f32_fp8(u, 1);
    r[2] = __builtin_amdgcn_cvt_f32_fp8(u, 2);
    r[3] = __builtin_amdgcn_cvt_f32_fp8(u, 3);
    return r;
}

__device__ __forceinline__ uint2 q8(f32x4_t a, f32x4_t b, float sc) {
    uint2 r;
    r.x = pk_fp8x4(a[0] * sc, a[1] * sc, a[2] * sc, a[3] * sc);
    r.y = pk_fp8x4(b[0] * sc, b[1] * sc, b[2] * sc, b[3] * sc);
    return r;
}

// c-frag address (verified R10): frag (ks=row0>>5, of=col>>4), slot=(col&15)+16*((row0>>3)&3)
__device__ __forceinline__ size_t cfrag_addr(int b, int row0, int col) {
    return ((size_t)(b * 64 + (row0 >> 5)) * 16 + (col >> 4)) * 512
         + ((col & 15) + 16 * ((row0 >> 3) & 3)) * 8 + (row0 & 4);
}

// ================= normadj: frag-major output via LDS transpose (verified R10) =================
__global__ __launch_bounds__(1024) void k_normadj(const float* __restrict__ adj,
                                                  unsigned char* __restrict__ afrag) {
    __shared__ __align__(16) unsigned char fr[64 * 520];
    const int w = threadIdx.x >> 6;
    const int l = threadIdx.x & 63;
    const int n = blockIdx.x * 16 + w;
    const float* src = adj + (size_t)n * NN;
    f32x4_t v[8];
#pragma unroll
    for (int q = 0; q < 4; ++q) {
        v[2 * q]     = *(const f32x4_t*)(src + q * 512 + l * 8);
        v[2 * q + 1] = *(const f32x4_t*)(src + q * 512 + l * 8 + 4);
    }
    float s = 0.f;
#pragma unroll
    for (int j = 0; j < 8; ++j) s += v[j][0] + v[j][1] + v[j][2] + v[j][3];
#pragma unroll
    for (int m = 1; m < 64; m <<= 1) s += __shfl_xor(s, m, 64);
    const float sc = 256.0f / (s + REPS);
#pragma unroll
    for (int q = 0; q < 4; ++q) {
        uint2 u = q8(v[2 * q], v[2 * q + 1], sc);
        *(uint2*)(fr + (16 * q + (l >> 2)) * 520 + w * 8 + (l & 3) * 128) = u;
    }
    __syncthreads();
    unsigned char* dst = afrag + (size_t)blockIdx.x * 64 * 512;
#pragma unroll
    for (int f2 = 0; f2 < 4; ++f2) {
        const int f = w * 4 + f2;
        *(uint2*)(dst + (size_t)f * 512 + l * 8) = *(const uint2*)(fr + f * 520 + l * 8);
    }
}

// ================= htrans: bf16x3 MFMA; t_h fp16, c0 frag-major (verified R10) =================
__device__ __forceinline__ void pair_remap(int& n0, int& o0, int& b) {
    const int p = blockIdx.x + 32 * (blockIdx.y + 2 * blockIdx.z);
    const int g = p >> 4, r = p & 15;
    o0 = (r >> 3) * 128;
    const int nb = g * 8 + (r & 7);
    n0 = (nb & 31) * 64;
    b  = nb >> 5;
}

__global__ __launch_bounds__(256) void k_htrans(const float* __restrict__ h,
                                                const float* __restrict__ W,
                                                _Float16* __restrict__ t_h,
                                                unsigned char* __restrict__ c0f) {
    __shared__ __align__(16) __bf16 Ah[64 * 64], Al[64 * 64];
    __shared__ __align__(16) __bf16 Bh[128 * 64], Bl[128 * 64];

    const int tid = threadIdx.x;
    int n0, o0, b;
    pair_remap(n0, o0, b);
    const int lane = tid & 63, wv = tid >> 6;
    const int wr = wv >> 1, wc = wv & 1;
    const int rl = lane & 15, kq = lane >> 4;
    const int ar = tid >> 4, ac = (tid & 15) * 4;

    f32x4_t acc[2][4];
#pragma unroll
    for (int i = 0; i < 2; ++i)
#pragma unroll
        for (int j = 0; j < 4; ++j) acc[i][j] = (f32x4_t){0.f, 0.f, 0.f, 0.f};

    for (int kt = 0; kt < 4; ++kt) {
        const int k0 = kt * 64;
#pragma unroll
        for (int q = 0; q < 4; ++q) {
            const int r = q * 16 + ar;
            f32x4_t v = *(const f32x4_t*)(h + ((size_t)b * NN + n0 + r) * DD + k0 + ac);
            bf16x4_t hi4, lo4;
#pragma unroll
            for (int e = 0; e < 4; ++e) {
                float x = v[e];
                __bf16 hh = (__bf16)x;
                hi4[e] = hh;
                lo4[e] = (__bf16)(x - (float)hh);
            }
            const int off = r * 128 + (((ac >> 3) ^ (r & 7)) << 4) + (ac & 7) * 2;
            *(bf16x4_t*)((char*)Ah + off) = hi4;
            *(bf16x4_t*)((char*)Al + off) = lo4;
        }
#pragma unroll
        for (int q = 0; q < 8; ++q) {
            const int r = q * 16 + ar;
            f32x4_t v = *(const f32x4_t*)(W + (size_t)(o0 + r) * DD + k0 + ac);
            bf16x4_t hi4, lo4;
#pragma unroll
            for (int e = 0; e < 4; ++e) {
                float x = v[e];
                __bf16 hh = (__bf16)x;
                hi4[e] = hh;
                lo4[e] = (__bf16)(x - (float)hh);
            }
            const int off = r * 128 + (((ac >> 3) ^ (r & 7)) << 4) + (ac & 7) * 2;
            *(bf16x4_t*)((char*)Bh + off) = hi4;
            *(bf16x4_t*)((char*)Bl + off) = lo4;
        }
        __syncthreads();
#pragma unroll
        for (int s = 0; s < 2; ++s) {
            bf16x8_t ah[2], al[2], bh[4], bl[4];
#pragma unroll
            for (int i = 0; i < 2; ++i) {
                const int row = wr * 32 + i * 16 + rl;
                const int byo = row * 128 + (((s * 4 + kq) ^ (row & 7)) << 4);
                ah[i] = *(const bf16x8_t*)((const char*)Ah + byo);
                al[i] = *(const bf16x8_t*)((const char*)Al + byo);
            }
#pragma unroll
            for (int j = 0; j < 4; ++j) {
                const int o = wc * 64 + j * 16 + rl;
                const int byo = o * 128 + (((s * 4 + kq) ^ (o & 7)) << 4);
                bh[j] = *(const bf16x8_t*)((const char*)Bh + byo);
                bl[j] = *(const bf16x8_t*)((const char*)Bl + byo);
            }
#pragma unroll
            for (int i = 0; i < 2; ++i)
#pragma unroll
                for (int j = 0; j < 4; ++j) {
                    acc[i][j] = __builtin_amdgcn_mfma_f32_16x16x32_bf16(ah[i], bh[j], acc[i][j], 0, 0, 0);
                    acc[i][j] = __builtin_amdgcn_mfma_f32_16x16x32_bf16(al[i], bh[j], acc[i][j], 0, 0, 0);
                    acc[i][j] = __builtin_amdgcn_mfma_f32_16x16x32_bf16(ah[i], bl[j], acc[i][j], 0, 0, 0);
                }
        }
        __syncthreads();
    }

#pragma unroll
    for (int i = 0; i < 2; ++i)
#pragma unroll
        for (int j = 0; j < 4; ++j) {
            const int row0 = n0 + wr * 32 + i * 16 + kq * 4;
            const int col  = o0 + wc * 64 + j * 16 + rl;
            _Float16* tp = t_h + ((size_t)b * NN + row0) * DD + col;
#pragma unroll
            for (int r2 = 0; r2 < 4; ++r2) tp[r2 * DD] = (_Float16)acc[i][j][r2];
            *(unsigned int*)(c0f + cfrag_addr(b, row0, col)) =
                pk_fp8x4(16.f * acc[i][j][0], 16.f * acc[i][j][1],
                         16.f * acc[i][j][2], 16.f * acc[i][j][3]);
        }
}

// ================= diffuse: frag-major LDS, NBUF=3, ahead-2 counted vmcnt =================
// tile 64n x 256o, BK=128, 512 thr / 8 waves (2 wr x 4 wc), wave = 32 x 64.
// A buf 8 KB = 16 frags (nfl*4+ks); B buf 32 KB = 64 frags (ks*16+of). 120 KB total.
template <bool LAST>
__global__ __launch_bounds__(512) void k_diffuse(const unsigned char* __restrict__ afrag,
                                                 const unsigned char* __restrict__ cin,
                                                 unsigned char* __restrict__ cout,
                                                 const unsigned char* __restrict__ c1f,
                                                 const unsigned char* __restrict__ c2f,
                                                 const _Float16* __restrict__ t_h,
                                                 float* __restrict__ out,
                                                 const float* __restrict__ convw,
                                                 const float* __restrict__ convb) {
    __shared__ __align__(16) unsigned char As[3][8192];    // 24 KB
    __shared__ __align__(16) unsigned char Bs[3][32768];   // 96 KB

    const int tid = threadIdx.x;
    const int n0 = blockIdx.x * 64, b = blockIdx.y;
    const int lane = tid & 63, wv = tid >> 6;
    const int wr = wv >> 2, wc = wv & 3;
    const int rl = lane & 15, kq = lane >> 4;

    // staging sources: wave wv's A chunk = frags (nfl=wv>>1, ks=(wv&1)*2 + {0,1})
    const unsigned char* aSrc = afrag
        + ((size_t)(b * 128 + (n0 >> 4) + (wv >> 1)) * 64 + (wv & 1) * 2) * 512 + lane * 16;
    const unsigned char* cSrc = cin + (size_t)b * 64 * 16 * 512 + wv * 4096 + lane * 16;

    f32x4_t acc[2][4];
#pragma unroll
    for (int i = 0; i < 2; ++i)
#pragma unroll
        for (int j = 0; j < 4; ++j) acc[i][j] = (f32x4_t){0.f, 0.f, 0.f, 0.f};

#define STAGE(T, BUF)                                                                  \
    {                                                                                  \
        const int tt = (T) & 15;                                                       \
        gl2lds16(aSrc + (size_t)tt * 2048, As[BUF] + wv * 1024);                       \
        const unsigned char* cs = cSrc + (size_t)tt * 32768;                           \
        gl2lds16(cs, Bs[BUF] + wv * 4096);                                             \
        gl2lds16(cs + 1024, Bs[BUF] + wv * 4096 + 1024);                               \
        gl2lds16(cs + 2048, Bs[BUF] + wv * 4096 + 2048);                               \
        gl2lds16(cs + 3072, Bs[BUF] + wv * 4096 + 3072);                               \
    }

    STAGE(0, 0)
    STAGE(1, 1)

    int bc = 0, bs = 2;   // compute buf = t%3, stage buf = (t+2)%3
    for (int t = 0; t < 16; ++t) {
        asm volatile("s_waitcnt vmcnt(5)" ::: "memory");   // tile t's 5 loads landed
        __builtin_amdgcn_s_barrier();                      // all waves' tile-t loads landed
        __builtin_amdgcn_sched_barrier(0);
        STAGE(t + 2, bs)                                   // safe: all finished compute(t-1)
        __builtin_amdgcn_sched_barrier(0);
        const unsigned char* Ac = As[bc];
        const unsigned char* Bc = Bs[bc];
#pragma unroll
        for (int s = 0; s < 4; ++s) {
            long a[2], bb[4];
#pragma unroll
            for (int i = 0; i < 2; ++i)
                a[i] = *(const long*)(Ac + ((wr * 2 + i) * 4 + s) * 512 + lane * 8);
#pragma unroll
            for (int j = 0; j < 4; ++j)
                bb[j] = *(const long*)(Bc + (s * 16 + wc * 4 + j) * 512 + lane * 8);
#pragma unroll
            for (int i = 0; i < 2; ++i)
#pragma unroll
                for (int j = 0; j < 4; ++j)
                    acc[i][j] = __builtin_amdgcn_mfma_f32_16x16x32_fp8_fp8(a[i], bb[j], acc[i][j], 0, 0, 0);
        }
        bc = (bc == 2) ? 0 : bc + 1;
        bs = (bs == 2) ? 0 : bs + 1;
    }
#undef STAGE

    // ---- epilogue: D frag col=lane&15, row=(lane>>4)*4+reg ----
#pragma unroll
    for (int i = 0; i < 2; ++i)
#pragma unroll
        for (int j = 0; j < 4; ++j) {
            const int row0 = n0 + (wr * 2 + i) * 16 + kq * 4;
            const int col  = wc * 64 + j * 16 + rl;
            if (LAST) {
                const float cw0 = convw[0], cw1 = convw[1], cw2 = convw[2], cw3 = convw[3];
                const float cb  = convb[0];
                const float ru = 1.0f / 16.0f, rf = 1.0f / 4096.0f;
                float* op = out + ((size_t)b * NN + row0) * DD + col;
                const _Float16* tp = t_h + ((size_t)b * NN + row0) * DD + col;
                const size_t sa = cfrag_addr(b, row0, col);
                f32x4_t u1 = cvt_f32_fp8x4(*(const unsigned int*)(c1f + sa));
                f32x4_t u2 = cvt_f32_fp8x4(*(const unsigned int*)(c2f + sa));
#pragma unroll
                for (int r2 = 0; r2 < 4; ++r2) {
                    float v = cw0 * (float)tp[r2 * DD] + cw1 * ru * u1[r2] + cw2 * ru * u2[r2]
                            + cw3 * rf * acc[i][j][r2] + cb;
                    op[r2 * DD] = v >= 0.0f ? v : SLOPE * v;
                }
            } else {
                const float rs = 1.0f / 256.0f;   // acc -> 16*c_next
                *(unsigned int*)(cout + cfrag_addr(b, row0, col)) =
                    pk_fp8x4(rs * acc[i][j][0], rs * acc[i][j][1],
                             rs * acc[i][j][2], rs * acc[i][j][3]);
            }
        }
}

extern "C" void kernel_launch(void* const* d_in, const int* in_sizes, int n_in,
                              void* d_out, int out_size, void* d_ws, size_t ws_size,
                              hipStream_t stream) {
    const float* h   = (const float*)d_in[0];
    const float* adj = (const float*)d_in[1];
    const float* W   = (const float*)d_in[2];
    const float* cw  = (const float*)d_in[3];
    const float* cb  = (const float*)d_in[4];
    float* out = (float*)d_out;

    char* ws = (char*)d_ws;
    unsigned char* afrag = (unsigned char*)ws;                        // 32 MB
    unsigned char* c0f   = (unsigned char*)(ws + 33554432);           // 4 MB
    unsigned char* c1f   = (unsigned char*)(ws + 37748736);           // 4 MB
    unsigned char* c2f   = (unsigned char*)(ws + 41943040);           // 4 MB
    _Float16*      t_h   = (_Float16*)(ws + 46137344);                // 8.4 MB (~52.5 MB)

    k_normadj<<<BATCH * NN / 16, 1024, 0, stream>>>(adj, afrag);
    k_htrans<<<dim3(32, 2, BATCH), 256, 0, stream>>>(h, W, t_h, c0f);
    k_diffuse<false><<<dim3(32, BATCH), 512, 0, stream>>>(afrag, c0f, c1f, nullptr, nullptr, nullptr, out, cw, cb);
    k_diffuse<false><<<dim3(32, BATCH), 512, 0, stream>>>(afrag, c1f, c2f, nullptr, nullptr, nullptr, out, cw, cb);
    k_diffuse<true ><<<dim3(32, BATCH), 512, 0, stream>>>(afrag, c2f, nullptr, c1f, c2f, t_h, out, cw, cb);
}

// Round 12
// 102.528 us; speedup vs baseline: 1.6360x; 1.0120x over previous
//
#include <hip/hip_runtime.h>
#include <hip/hip_bf16.h>
#include <cstdint>

// MultiRelationalGraphDiffusion: out = LeakyReLU( sum_k conv_w[k] * (adj_norm^k @ (h@W^T)) + conv_b )
// B=8, N=2048, D=256, K=4.
//
// Round-12: R11 (frag-major LDS + counted vmcnt, 103.8us) with diffuse at 2 BLOCKS/CU.
// R11 deficit: 120 KB LDS -> 1 blk/CU, 2 waves/SIMD, 256 blocks = 1/CU -> barrier stalls
// uncovered. Fix: o-split tile 64n x 128o, NBUF=3 x (A 8KB + B 16KB) = 72 KB -> 2 blk/CU
// (4 waves/SIMD); grid 512 with XCD pair remap (o-halves 8 IDs apart -> A re-read L2-hit).
// Sync order copied verbatim from R11 (proven): vmcnt(3) -> s_barrier -> stage(t+2 ->
// buf (t+2)%3) -> compute(t). Ledger: staged buf last read at compute(t-1), which every
// wave finished before barrier(t). 3 uniform loads/wave/tile -> vmcnt(3) leaves tile t+1
// in flight (1-tile cover, validated in R11).
// Scales: adjS=256*adj_norm, cS=16*c -> acc=4096*(adj@c); next cS=acc/256; last tap acc/4096.

#define BATCH 8
#define NN    2048
#define DD    256
#define REPS  1e-9f
#define SLOPE 0.2f

typedef __bf16 bf16x8_t __attribute__((ext_vector_type(8)));
typedef __bf16 bf16x4_t __attribute__((ext_vector_type(4)));
typedef float  f32x4_t  __attribute__((ext_vector_type(4)));

__device__ __forceinline__ void gl2lds16(const void* g, void* l) {
    __builtin_amdgcn_global_load_lds(
        (const __attribute__((address_space(1))) unsigned int*)(uintptr_t)g,
        (__attribute__((address_space(3))) unsigned int*)(unsigned int)(uintptr_t)l,
        16, 0, 0);
}

__device__ __forceinline__ unsigned int pk_fp8x4(float a, float b, float c, float d) {
    int lo = __builtin_amdgcn_cvt_pk_fp8_f32(a, b, 0, false);
    return (unsigned int)__builtin_amdgcn_cvt_pk_fp8_f32(c, d, lo, true);
}

__device__ __forceinline__ f32x4_t cvt_f32_fp8x4(unsigned int u) {
    f32x4_t r;
    r[0] = __builtin_amdgcn_cvt_f32_fp8(u, 0);
    r[1] = __builtin_amdgcn_cvt_f32_fp8(u, 1);
    r[2] = __builtin_amdgcn_cvt_f32_fp8(u, 2);
    r[3] = __builtin_amdgcn_cvt_f32_fp8(u, 3);
    return r;
}

__device__ __forceinline__ uint2 q8(f32x4_t a, f32x4_t b, float sc) {
    uint2 r;
    r.x = pk_fp8x4(a[0] * sc, a[1] * sc, a[2] * sc, a[3] * sc);
    r.y = pk_fp8x4(b[0] * sc, b[1] * sc, b[2] * sc, b[3] * sc);
    return r;
}

// c-frag address (verified R10/R11)
__device__ __forceinline__ size_t cfrag_addr(int b, int row0, int col) {
    return ((size_t)(b * 64 + (row0 >> 5)) * 16 + (col >> 4)) * 512
         + ((col & 15) + 16 * ((row0 >> 3) & 3)) * 8 + (row0 & 4);
}

// ================= normadj: frag-major output via LDS transpose (verified R10/R11) =================
__global__ __launch_bounds__(1024) void k_normadj(const float* __restrict__ adj,
                                                  unsigned char* __restrict__ afrag) {
    __shared__ __align__(16) unsigned char fr[64 * 520];
    const int w = threadIdx.x >> 6;
    const int l = threadIdx.x & 63;
    const int n = blockIdx.x * 16 + w;
    const float* src = adj + (size_t)n * NN;
    f32x4_t v[8];
#pragma unroll
    for (int q = 0; q < 4; ++q) {
        v[2 * q]     = *(const f32x4_t*)(src + q * 512 + l * 8);
        v[2 * q + 1] = *(const f32x4_t*)(src + q * 512 + l * 8 + 4);
    }
    float s = 0.f;
#pragma unroll
    for (int j = 0; j < 8; ++j) s += v[j][0] + v[j][1] + v[j][2] + v[j][3];
#pragma unroll
    for (int m = 1; m < 64; m <<= 1) s += __shfl_xor(s, m, 64);
    const float sc = 256.0f / (s + REPS);
#pragma unroll
    for (int q = 0; q < 4; ++q) {
        uint2 u = q8(v[2 * q], v[2 * q + 1], sc);
        *(uint2*)(fr + (16 * q + (l >> 2)) * 520 + w * 8 + (l & 3) * 128) = u;
    }
    __syncthreads();
    unsigned char* dst = afrag + (size_t)blockIdx.x * 64 * 512;
#pragma unroll
    for (int f2 = 0; f2 < 4; ++f2) {
        const int f = w * 4 + f2;
        *(uint2*)(dst + (size_t)f * 512 + l * 8) = *(const uint2*)(fr + f * 520 + l * 8);
    }
}

// ================= htrans: bf16x3 MFMA; t_h fp16, c0 frag-major (verified R10/R11) =================
__device__ __forceinline__ void pair_remap(int& n0, int& o0, int& b) {
    const int p = blockIdx.x + 32 * (blockIdx.y + 2 * blockIdx.z);
    const int g = p >> 4, r = p & 15;
    o0 = (r >> 3) * 128;
    const int nb = g * 8 + (r & 7);
    n0 = (nb & 31) * 64;
    b  = nb >> 5;
}

__global__ __launch_bounds__(256) void k_htrans(const float* __restrict__ h,
                                                const float* __restrict__ W,
                                                _Float16* __restrict__ t_h,
                                                unsigned char* __restrict__ c0f) {
    __shared__ __align__(16) __bf16 Ah[64 * 64], Al[64 * 64];
    __shared__ __align__(16) __bf16 Bh[128 * 64], Bl[128 * 64];

    const int tid = threadIdx.x;
    int n0, o0, b;
    pair_remap(n0, o0, b);
    const int lane = tid & 63, wv = tid >> 6;
    const int wr = wv >> 1, wc = wv & 1;
    const int rl = lane & 15, kq = lane >> 4;
    const int ar = tid >> 4, ac = (tid & 15) * 4;

    f32x4_t acc[2][4];
#pragma unroll
    for (int i = 0; i < 2; ++i)
#pragma unroll
        for (int j = 0; j < 4; ++j) acc[i][j] = (f32x4_t){0.f, 0.f, 0.f, 0.f};

    for (int kt = 0; kt < 4; ++kt) {
        const int k0 = kt * 64;
#pragma unroll
        for (int q = 0; q < 4; ++q) {
            const int r = q * 16 + ar;
            f32x4_t v = *(const f32x4_t*)(h + ((size_t)b * NN + n0 + r) * DD + k0 + ac);
            bf16x4_t hi4, lo4;
#pragma unroll
            for (int e = 0; e < 4; ++e) {
                float x = v[e];
                __bf16 hh = (__bf16)x;
                hi4[e] = hh;
                lo4[e] = (__bf16)(x - (float)hh);
            }
            const int off = r * 128 + (((ac >> 3) ^ (r & 7)) << 4) + (ac & 7) * 2;
            *(bf16x4_t*)((char*)Ah + off) = hi4;
            *(bf16x4_t*)((char*)Al + off) = lo4;
        }
#pragma unroll
        for (int q = 0; q < 8; ++q) {
            const int r = q * 16 + ar;
            f32x4_t v = *(const f32x4_t*)(W + (size_t)(o0 + r) * DD + k0 + ac);
            bf16x4_t hi4, lo4;
#pragma unroll
            for (int e = 0; e < 4; ++e) {
                float x = v[e];
                __bf16 hh = (__bf16)x;
                hi4[e] = hh;
                lo4[e] = (__bf16)(x - (float)hh);
            }
            const int off = r * 128 + (((ac >> 3) ^ (r & 7)) << 4) + (ac & 7) * 2;
            *(bf16x4_t*)((char*)Bh + off) = hi4;
            *(bf16x4_t*)((char*)Bl + off) = lo4;
        }
        __syncthreads();
#pragma unroll
        for (int s = 0; s < 2; ++s) {
            bf16x8_t ah[2], al[2], bh[4], bl[4];
#pragma unroll
            for (int i = 0; i < 2; ++i) {
                const int row = wr * 32 + i * 16 + rl;
                const int byo = row * 128 + (((s * 4 + kq) ^ (row & 7)) << 4);
                ah[i] = *(const bf16x8_t*)((const char*)Ah + byo);
                al[i] = *(const bf16x8_t*)((const char*)Al + byo);
            }
#pragma unroll
            for (int j = 0; j < 4; ++j) {
                const int o = wc * 64 + j * 16 + rl;
                const int byo = o * 128 + (((s * 4 + kq) ^ (o & 7)) << 4);
                bh[j] = *(const bf16x8_t*)((const char*)Bh + byo);
                bl[j] = *(const bf16x8_t*)((const char*)Bl + byo);
            }
#pragma unroll
            for (int i = 0; i < 2; ++i)
#pragma unroll
                for (int j = 0; j < 4; ++j) {
                    acc[i][j] = __builtin_amdgcn_mfma_f32_16x16x32_bf16(ah[i], bh[j], acc[i][j], 0, 0, 0);
                    acc[i][j] = __builtin_amdgcn_mfma_f32_16x16x32_bf16(al[i], bh[j], acc[i][j], 0, 0, 0);
                    acc[i][j] = __builtin_amdgcn_mfma_f32_16x16x32_bf16(ah[i], bl[j], acc[i][j], 0, 0, 0);
                }
        }
        __syncthreads();
    }

#pragma unroll
    for (int i = 0; i < 2; ++i)
#pragma unroll
        for (int j = 0; j < 4; ++j) {
            const int row0 = n0 + wr * 32 + i * 16 + kq * 4;
            const int col  = o0 + wc * 64 + j * 16 + rl;
            _Float16* tp = t_h + ((size_t)b * NN + row0) * DD + col;
#pragma unroll
            for (int r2 = 0; r2 < 4; ++r2) tp[r2 * DD] = (_Float16)acc[i][j][r2];
            *(unsigned int*)(c0f + cfrag_addr(b, row0, col)) =
                pk_fp8x4(16.f * acc[i][j][0], 16.f * acc[i][j][1],
                         16.f * acc[i][j][2], 16.f * acc[i][j][3]);
        }
}

// ================= diffuse: frag-major LDS, o-split, 2 blocks/CU, counted vmcnt =================
// tile 64n x 128o, BK=128, 512 thr / 8 waves (wr 0..3 x wc 0..1), wave = 16 x 64.
// A buf 8 KB (frag (nfl,ksl) at nfl*2048+ksl*512); B buf 16 KB (frag (ksl,ofl) at
// ksl*4096+ofl*512). NBUF=3 -> 72 KB -> 2 blocks/CU. 3 loads/wave/tile (1 A + 2 B).
template <bool LAST>
__global__ __launch_bounds__(512) void k_diffuse(const unsigned char* __restrict__ afrag,
                                                 const unsigned char* __restrict__ cin,
                                                 unsigned char* __restrict__ cout,
                                                 const unsigned char* __restrict__ c1f,
                                                 const unsigned char* __restrict__ c2f,
                                                 const _Float16* __restrict__ t_h,
                                                 float* __restrict__ out,
                                                 const float* __restrict__ convw,
                                                 const float* __restrict__ convb) {
    __shared__ __align__(16) unsigned char As[3][8192];    // 24 KB
    __shared__ __align__(16) unsigned char Bs[3][16384];   // 48 KB

    const int tid = threadIdx.x;
    // XCD pair remap: o-halves of one (n0,b) are 8 block-IDs apart -> same XCD
    const int p = blockIdx.x;
    const int g = p >> 4, r = p & 15;
    const int oh = r >> 3;
    const int nb = g * 8 + (r & 7);
    const int n0 = (nb & 31) * 64, b = nb >> 5;

    const int lane = tid & 63, wv = tid >> 6;
    const int wr = wv >> 1, wc = wv & 1;
    const int rl = lane & 15, kq = lane >> 4;

    // staging sources: wave wv -> A frag group nfl=wr (half wv&1), B ks-group ksl=wr
    const unsigned char* aSrc = afrag
        + ((size_t)(b * 128 + (n0 >> 4) + wr) * 64) * 512 + (wv & 1) * 1024 + lane * 16;
    const unsigned char* cSrc = cin
        + ((size_t)(b * 64) * 16 + oh * 8) * 512 + (wv & 1) * 2048 + lane * 16;

    f32x4_t acc[4];
#pragma unroll
    for (int j = 0; j < 4; ++j) acc[j] = (f32x4_t){0.f, 0.f, 0.f, 0.f};

#define STAGE(T, BUF)                                                                  \
    {                                                                                  \
        const int tt = (T) & 15;                                                       \
        gl2lds16(aSrc + (size_t)tt * 2048, As[BUF] + wr * 2048 + (wv & 1) * 1024);     \
        const unsigned char* cs = cSrc + (size_t)(tt * 4 + wr) * 8192;                 \
        gl2lds16(cs, Bs[BUF] + wr * 4096 + (wv & 1) * 2048);                           \
        gl2lds16(cs + 1024, Bs[BUF] + wr * 4096 + (wv & 1) * 2048 + 1024);             \
    }

    STAGE(0, 0)
    STAGE(1, 1)

    int bc = 0, bs = 2;   // compute buf = t%3, stage buf = (t+2)%3
    for (int t = 0; t < 16; ++t) {
        asm volatile("s_waitcnt vmcnt(3)" ::: "memory");   // tile t's 3 loads landed
        __builtin_amdgcn_s_barrier();                      // all waves' tile-t loads landed
        __builtin_amdgcn_sched_barrier(0);
        STAGE(t + 2, bs)                                   // safe: all finished compute(t-1)
        __builtin_amdgcn_sched_barrier(0);
        const unsigned char* Ac = As[bc];
        const unsigned char* Bc = Bs[bc];
#pragma unroll
        for (int s = 0; s < 4; ++s) {
            long a = *(const long*)(Ac + (wr * 4 + s) * 512 + lane * 8);
            long bb[4];
#pragma unroll
            for (int j = 0; j < 4; ++j)
                bb[j] = *(const long*)(Bc + (s * 8 + wc * 4 + j) * 512 + lane * 8);
#pragma unroll
            for (int j = 0; j < 4; ++j)
                acc[j] = __builtin_amdgcn_mfma_f32_16x16x32_fp8_fp8(a, bb[j], acc[j], 0, 0, 0);
        }
        bc = (bc == 2) ? 0 : bc + 1;
        bs = (bs == 2) ? 0 : bs + 1;
    }
#undef STAGE

    // ---- epilogue: D frag col=lane&15, row=(lane>>4)*4+reg ----
#pragma unroll
    for (int j = 0; j < 4; ++j) {
        const int row0 = n0 + wr * 16 + kq * 4;
        const int col  = oh * 128 + wc * 64 + j * 16 + rl;
        if (LAST) {
            const float cw0 = convw[0], cw1 = convw[1], cw2 = convw[2], cw3 = convw[3];
            const float cb  = convb[0];
            const float ru = 1.0f / 16.0f, rf = 1.0f / 4096.0f;
            float* op = out + ((size_t)b * NN + row0) * DD + col;
            const _Float16* tp = t_h + ((size_t)b * NN + row0) * DD + col;
            const size_t sa = cfrag_addr(b, row0, col);
            f32x4_t u1 = cvt_f32_fp8x4(*(const unsigned int*)(c1f + sa));
            f32x4_t u2 = cvt_f32_fp8x4(*(const unsigned int*)(c2f + sa));
#pragma unroll
            for (int r2 = 0; r2 < 4; ++r2) {
                float v = cw0 * (float)tp[r2 * DD] + cw1 * ru * u1[r2] + cw2 * ru * u2[r2]
                        + cw3 * rf * acc[j][r2] + cb;
                op[r2 * DD] = v >= 0.0f ? v : SLOPE * v;
            }
        } else {
            const float rs = 1.0f / 256.0f;   // acc -> 16*c_next
            *(unsigned int*)(cout + cfrag_addr(b, row0, col)) =
                pk_fp8x4(rs * acc[j][0], rs * acc[j][1], rs * acc[j][2], rs * acc[j][3]);
        }
    }
}

extern "C" void kernel_launch(void* const* d_in, const int* in_sizes, int n_in,
                              void* d_out, int out_size, void* d_ws, size_t ws_size,
                              hipStream_t stream) {
    const float* h   = (const float*)d_in[0];
    const float* adj = (const float*)d_in[1];
    const float* W   = (const float*)d_in[2];
    const float* cw  = (const float*)d_in[3];
    const float* cb  = (const float*)d_in[4];
    float* out = (float*)d_out;

    char* ws = (char*)d_ws;
    unsigned char* afrag = (unsigned char*)ws;                        // 32 MB
    unsigned char* c0f   = (unsigned char*)(ws + 33554432);           // 4 MB
    unsigned char* c1f   = (unsigned char*)(ws + 37748736);           // 4 MB
    unsigned char* c2f   = (unsigned char*)(ws + 41943040);           // 4 MB
    _Float16*      t_h   = (_Float16*)(ws + 46137344);                // 8.4 MB (~52.5 MB)

    k_normadj<<<BATCH * NN / 16, 1024, 0, stream>>>(adj, afrag);
    k_htrans<<<dim3(32, 2, BATCH), 256, 0, stream>>>(h, W, t_h, c0f);
    k_diffuse<false><<<512, 512, 0, stream>>>(afrag, c0f, c1f, nullptr, nullptr, nullptr, out, cw, cb);
    k_diffuse<false><<<512, 512, 0, stream>>>(afrag, c1f, c2f, nullptr, nullptr, nullptr, out, cw, cb);
    k_diffuse<true ><<<512, 512, 0, stream>>>(afrag, c2f, nullptr, c1f, c2f, t_h, out, cw, cb);
}